// Round 8
// baseline (476.146 us; speedup 1.0000x reference)
//
#include <hip/hip_runtime.h>
#include <cstdint>
#include <cmath>

// Sudoku iterative-solver, one wave/board, fp64 decisions (R7-validated).
// R8: latency-path surgery.
//  - absmax 4.882812e-4 == harness floor (bit-identical R1/R2/R5/R7) — all
//    passing rounds match np decisions; fp64 keeps it deterministic.
//  - Phase C: incremental fp64 pre-activations in REGISTERS (compile-time
//    indexed via unrolled uniform branches); cnt RMW deleted.
//  - Phase D: scatter pp + owner-sum (b128, 4 accs); softmax via 2 LDS
//    round-trips (local ymax/argmax, one exp/lane, local ascending S);
//    score = 1/S (stabilizer = true row max => smax == 1/S exactly).
//  - Phase A: fp64 butterfly (6 hops) — kept; gaps can be ~1e-6..1e-9,
//    fp32 packing too risky (R4 lesson).

__device__ __forceinline__ void wave_fence() {
  asm volatile("s_waitcnt lgkmcnt(0)" ::: "memory");
}

__device__ __forceinline__ int dist_row(int i) {
  int r = i / 27;
  int t = i - 27 * r;
  if (r == 0) return t / 3;
  if (r == 1) return 9 + (t % 3);
  return 12 + 3 * (t / 9) + (t % 3);
}

// uniform-index select from a register array (b0d..b3d = bits of idx, idx<=8)
#define SEL9C(A, B)                                                          \
  (b3d ? A[(B) + 8]                                                          \
       : (b2d ? (b1d ? (b0d ? A[(B) + 7] : A[(B) + 6])                       \
                     : (b0d ? A[(B) + 5] : A[(B) + 4]))                      \
              : (b1d ? (b0d ? A[(B) + 3] : A[(B) + 2])                       \
                     : (b0d ? A[(B) + 1] : A[(B) + 0]))))

__global__ __launch_bounds__(64, 2)
void sudoku_solver(const float* __restrict__ x, const float* __restrict__ W1g,
                   const float* __restrict__ W2g, float* __restrict__ out) {
  __shared__ double pp[27][65];     // Phase-D partials (pad 65: 2-way banks)
  __shared__ double ylds[32];       // y per slot (27 used)
  __shared__ double elds[32];       // exp per slot
  __shared__ float  cnt[3][9][12];  // init-only digit counts
  __shared__ float  sful[21][12];   // cached softmax rows (fp32 of fp64)
  __shared__ int    rargsL[24];     // per-row argmax digit
  __shared__ int    digc[81];

  const int lane = threadIdx.x;     // 0..63
  const int b = blockIdx.x;
  const float* xb = x + b * 729;
  float* ob = out + b * 729;

  // W1 rows fp32 (delta source); W2 columns fp64
  float w1a[27], w1b[27];
  #pragma unroll
  for (int c = 0; c < 27; ++c) {
    w1a[c] = W1g[lane * 27 + c];
    w1b[c] = W1g[(lane + 64) * 27 + c];
  }
  double w2Ad[9], w2Bd[9];
  #pragma unroll
  for (int d = 0; d < 9; ++d) {
    w2Ad[d] = (double)W2g[d * 128 + lane];
    w2Bd[d] = (double)W2g[d * 128 + 64 + lane];
  }

  for (int idx = lane; idx < 3 * 9 * 12; idx += 64)
    ((float*)cnt)[idx] = 0.f;

  // read board, ob = x, digits, empty flags
  bool eA, eB = false;
  {
    float v[9]; int dg = -1;
    #pragma unroll
    for (int e = 0; e < 9; ++e) v[e] = xb[lane * 9 + e];
    #pragma unroll
    for (int e = 0; e < 9; ++e) { if (v[e] > 0.5f) dg = e; ob[lane * 9 + e] = v[e]; }
    eA = (dg < 0); digc[lane] = dg;
    if (lane < 17) {
      const int i2 = 64 + lane;
      float w[9]; int dg2 = -1;
      #pragma unroll
      for (int e = 0; e < 9; ++e) w[e] = xb[i2 * 9 + e];
      #pragma unroll
      for (int e = 0; e < 9; ++e) { if (w[e] > 0.5f) dg2 = e; ob[i2 * 9 + e] = w[e]; }
      eB = (dg2 < 0); digc[i2] = dg2;
    }
  }
  const int distA = dist_row(lane);
  const int distB = (lane < 17) ? dist_row(64 + lane) : 255;
  const int srow = lane / 9;        // slot row (lane<27)
  const int sdig = lane - 9 * srow; // slot digit
  wave_fence();

  // initial group counts (27 lanes)
  if (lane < 27) {
    float c9[9];
    #pragma unroll
    for (int e = 0; e < 9; ++e) c9[e] = 0.f;
    #pragma unroll
    for (int k = 0; k < 9; ++k) {
      int cell;
      if (srow == 0)      cell = sdig * 9 + k;
      else if (srow == 1) cell = k * 9 + sdig;
      else cell = (sdig / 3) * 27 + (sdig % 3) * 3 + (k / 3) * 9 + (k % 3);
      const int dg = digc[cell];
      #pragma unroll
      for (int e = 0; e < 9; ++e) c9[e] += (dg == e) ? 1.f : 0.f;
    }
    #pragma unroll
    for (int e = 0; e < 9; ++e) cnt[srow][sdig][e] = c9[e];
  }
  wave_fence();

  double pre_a[21], pre_b[21];      // fp64 pre-activation cache (registers)
  double myscoreA = 0.0, myscoreB = 0.0;

  // Phase D: scatter + owner-sum + 2-round-trip softmax; updates caches.
  auto phaseD = [&](int u0, int u1, int u2,
                    double hA0, double hA1, double hA2,
                    double hB0, double hB1, double hB2) {
    #pragma unroll
    for (int dd = 0; dd < 9; ++dd) {
      pp[dd][lane]      = fma(hA0, w2Ad[dd], hB0 * w2Bd[dd]);
      pp[9 + dd][lane]  = fma(hA1, w2Ad[dd], hB1 * w2Bd[dd]);
      pp[18 + dd][lane] = fma(hA2, w2Ad[dd], hB2 * w2Bd[dd]);
    }
    wave_fence();
    if (lane < 27) {
      const double2* prow = (const double2*)&pp[lane][0];
      double a0 = 0.0, a1 = 0.0, a2 = 0.0, a3 = 0.0;
      #pragma unroll
      for (int g = 0; g < 32; g += 4) {
        const double2 v0 = prow[g],     v1 = prow[g + 1];
        const double2 v2 = prow[g + 2], v3 = prow[g + 3];
        a0 += v0.x + v0.y; a1 += v1.x + v1.y;
        a2 += v2.x + v2.y; a3 += v3.x + v3.y;
      }
      ylds[lane] = (a0 + a1) + (a2 + a3);
    }
    wave_fence();
    double S = 1.0, sval = 0.0;     // defaults for lanes >= 27
    if (lane < 27) {
      const double* yrow = &ylds[9 * srow];
      double y9[9];
      #pragma unroll
      for (int k = 0; k < 9; ++k) y9[k] = yrow[k];
      double ymax = y9[0]; int yarg = 0;
      #pragma unroll
      for (int k = 1; k < 9; ++k) {
        const bool g = y9[k] > ymax;   // strict > keeps first max (== np argmax)
        ymax = g ? y9[k] : ymax;
        yarg = g ? k : yarg;
      }
      if (sdig == 0) {
        const int us = (srow == 0) ? u0 : (srow == 1) ? u1 : u2;
        rargsL[us] = yarg;
      }
      elds[lane] = exp(y9[sdig] - ymax);
    }
    wave_fence();
    if (lane < 27) {
      const double* erow = &elds[9 * srow];
      double acc = erow[0];
      #pragma unroll
      for (int k = 1; k < 9; ++k) acc += erow[k];   // ascending (np order)
      S = acc;
      sval = elds[lane] / S;
      const int us = (srow == 0) ? u0 : (srow == 1) ? u1 : u2;
      sful[us][sdig] = (float)sval;
    }
    // row scores: smax == exp(0)/S == 1/S (stabilizer is the true row max)
    const double sc0 = __shfl(1.0 / S, 0);
    const double sc1 = __shfl(1.0 / S, 9);
    const double sc2 = __shfl(1.0 / S, 18);
    myscoreA = (distA == u0) ? sc0 : (distA == u1) ? sc1
             : (distA == u2) ? sc2 : myscoreA;
    myscoreB = (distB == u0) ? sc0 : (distB == u1) ? sc1
             : (distB == u2) ? sc2 : myscoreB;
    wave_fence();
  };

  // ---- initial 21 rows: fresh fp64 dots seed the register pre cache ----
  #pragma unroll
  for (int p = 0; p < 7; ++p) {
    double hAv[3], hBv[3];
    #pragma unroll
    for (int rr = 0; rr < 3; ++rr) {
      const int u = 3 * p + rr;     // compile-time
      int g, gia, gib, gic;
      if (u < 9)       { g = 0; gia = gib = gic = u; }
      else if (u < 12) { g = 1; gia = 3 * (u - 9); gib = gia + 1; gic = gia + 2; }
      else             { g = 2; gia = gib = gic = u - 12; }
      const float* f0 = &cnt[g][gia][0];
      const float* f1 = &cnt[g][gib][0];
      const float* f2 = &cnt[g][gic][0];
      double a0 = 0.0, a1 = 0.0;
      #pragma unroll
      for (int c = 0; c < 9; ++c) {
        const double fv = (double)f0[c];
        a0 = fma(fv, (double)w1a[c], a0); a1 = fma(fv, (double)w1b[c], a1);
      }
      #pragma unroll
      for (int c = 0; c < 9; ++c) {
        const double fv = (double)f1[c];
        a0 = fma(fv, (double)w1a[9 + c], a0); a1 = fma(fv, (double)w1b[9 + c], a1);
      }
      #pragma unroll
      for (int c = 0; c < 9; ++c) {
        const double fv = (double)f2[c];
        a0 = fma(fv, (double)w1a[18 + c], a0); a1 = fma(fv, (double)w1b[18 + c], a1);
      }
      pre_a[u] = a0; pre_b[u] = a1;
      hAv[rr] = fmax(a0, 0.0); hBv[rr] = fmax(a1, 0.0);
    }
    phaseD(3 * p, 3 * p + 1, 3 * p + 2,
           hAv[0], hAv[1], hAv[2], hBv[0], hBv[1], hBv[2]);
  }

  // ---- solver steps ----
  #pragma unroll 1
  for (int step = 0; step < 81; ++step) {
    // Phase A: fp64 wave argmax over empty cells (max score, first index)
    const double sA = eA ? myscoreA : 0.0;
    const double sB = (lane < 17 && eB) ? myscoreB : 0.0;
    double M = fmax(sA, sB);
    M = fmax(M, __shfl_xor(M, 1));
    M = fmax(M, __shfl_xor(M, 2));
    M = fmax(M, __shfl_xor(M, 4));
    M = fmax(M, __shfl_xor(M, 8));
    M = fmax(M, __shfl_xor(M, 16));
    M = fmax(M, __shfl_xor(M, 32));
    if (M <= 0.0) break;

    const unsigned long long m0 = __ballot(sA == M);
    const unsigned long long m1 = __ballot((lane < 17) && (sB == M));
    const int mmax = m0 ? __builtin_ctzll(m0) : 64 + __builtin_ctzll(m1);

    const int du = dist_row(mmax);
    const int digit = rargsL[du];           // LDS broadcast read
    const int r = mmax / 9, c = mmax - 9 * r;
    const int bx = (mmax / 27) * 3 + c / 3;
    const int q3 = c - 3 * (c / 3);

    // Phase B: output write for the filled cell; clear empty flags
    if (lane >= 8 && lane < 17)
      ob[mmax * 9 + (lane - 8)] = sful[du][lane - 8];
    if (lane == mmax) eA = false;
    if (lane + 64 == mmax) eB = false;
    wave_fence();

    // Phase C: incremental fp64 register pre update (uniform branches,
    // compile-time register indices)
    const int u0 = r, u1 = 9 + c / 3, u2 = 12 + bx;
    const bool b0d = digit & 1, b1d = digit & 2, b2d = digit & 4, b3d = digit & 8;
    const float ca0 = SEL9C(w1a, 0), ca1 = SEL9C(w1a, 9), ca2 = SEL9C(w1a, 18);
    const float cb0 = SEL9C(w1b, 0), cb1 = SEL9C(w1b, 9), cb2 = SEL9C(w1b, 18);
    const double d02a = (double)ca0 + (double)ca1 + (double)ca2;
    const double d02b = (double)cb0 + (double)cb1 + (double)cb2;
    const double d1a = (double)((q3 == 0) ? ca0 : ((q3 == 1) ? ca1 : ca2));
    const double d1b = (double)((q3 == 0) ? cb0 : ((q3 == 1) ? cb1 : cb2));

    double hA0 = 0.0, hB0 = 0.0, hA1 = 0.0, hB1 = 0.0, hA2 = 0.0, hB2 = 0.0;
    #pragma unroll
    for (int u = 0; u < 9; ++u)
      if (u == u0) {
        pre_a[u] += d02a; pre_b[u] += d02b;
        hA0 = fmax(pre_a[u], 0.0); hB0 = fmax(pre_b[u], 0.0);
      }
    #pragma unroll
    for (int u = 9; u < 12; ++u)
      if (u == u1) {
        pre_a[u] += d1a; pre_b[u] += d1b;
        hA1 = fmax(pre_a[u], 0.0); hB1 = fmax(pre_b[u], 0.0);
      }
    #pragma unroll
    for (int u = 12; u < 21; ++u)
      if (u == u2) {
        pre_a[u] += d02a; pre_b[u] += d02b;
        hA2 = fmax(pre_a[u], 0.0); hB2 = fmax(pre_b[u], 0.0);
      }

    phaseD(u0, u1, u2, hA0, hA1, hA2, hB0, hB1, hB2);
  }
}

extern "C" void kernel_launch(void* const* d_in, const int* in_sizes, int n_in,
                              void* d_out, int out_size, void* d_ws, size_t ws_size,
                              hipStream_t stream) {
  const float* x  = (const float*)d_in[0];   // [2048][81][9]
  const float* W1 = (const float*)d_in[1];   // [128][27]
  const float* W2 = (const float*)d_in[2];   // [9][128]
  float* out = (float*)d_out;                // [2048][81][9]
  sudoku_solver<<<dim3(2048), dim3(64), 0, stream>>>(x, W1, W2, out);
}

// Round 9
// 277.577 us; speedup vs baseline: 1.7154x; 1.7154x over previous
//
#include <hip/hip_runtime.h>
#include <cstdint>
#include <cmath>

// Sudoku iterative-solver, one wave/board, fp64 decisions.
// R9 = R7's no-spill skeleton (fresh fp64 Phase C from exact integer counts)
//  + R8's validated LDS-round-trip softmax (score = 1/S, y-argmax)
//  + NEW all-VALU-dominant Phase A: positive-double bits are u64-monotone;
//    butterfly on (hi,lo) u32 pair via 4 DPP steps + xor16 swizzle + xor32
//  + compiler-barriers only (single wave: DS ops are in-order per wave;
//    use-waits inserted by compiler) — no lgkmcnt(0) drains.
// absmax floor = 4.882812e-4 (harness bf16 comparison floor, bit-identical
// across R1/R2/R5/R7/R8) — expect exactly that value when decisions match np.

__device__ __forceinline__ void cbar() { asm volatile("" ::: "memory"); }

__device__ __forceinline__ int dist_row(int i) {
  int r = i / 27;
  int t = i - 27 * r;
  if (r == 0) return t / 3;
  if (r == 1) return 9 + (t % 3);
  return 12 + 3 * (t / 9) + (t % 3);
}

__global__ __launch_bounds__(64, 2)
void sudoku_solver(const float* __restrict__ x, const float* __restrict__ W1g,
                   const float* __restrict__ W2g, float* __restrict__ out) {
  __shared__ double pp[27][66];     // Phase-D partials; pad 66: 16B-aligned rows
  __shared__ double ylds[32];       // y per slot (27 used)
  __shared__ double elds[32];       // exp per slot
  __shared__ double rscoreL[21];    // per-row max softmax (== 1/S)
  __shared__ float  cnt[3][9][12];  // exact integer digit counts
  __shared__ float  sful[21][12];   // cached softmax rows (fp32 of fp64)
  __shared__ int    rargsL[24];     // per-row argmax digit
  __shared__ int    digc[81];

  const int lane = threadIdx.x;     // 0..63
  const int b = blockIdx.x;
  const float* xb = x + b * 729;
  float* ob = out + b * 729;

  // W1 rows fp32; W2 columns fp64 (R7 register profile, proven no-spill)
  float w1a[27], w1b[27];
  #pragma unroll
  for (int c = 0; c < 27; ++c) {
    w1a[c] = W1g[lane * 27 + c];
    w1b[c] = W1g[(lane + 64) * 27 + c];
  }
  double w2Ad[9], w2Bd[9];
  #pragma unroll
  for (int d = 0; d < 9; ++d) {
    w2Ad[d] = (double)W2g[d * 128 + lane];
    w2Bd[d] = (double)W2g[d * 128 + 64 + lane];
  }

  for (int idx = lane; idx < 3 * 9 * 12; idx += 64)
    ((float*)cnt)[idx] = 0.f;

  // read board, ob = x, digits, empty flags
  bool eA, eB = false;
  {
    float v[9]; int dg = -1;
    #pragma unroll
    for (int e = 0; e < 9; ++e) v[e] = xb[lane * 9 + e];
    #pragma unroll
    for (int e = 0; e < 9; ++e) { if (v[e] > 0.5f) dg = e; ob[lane * 9 + e] = v[e]; }
    eA = (dg < 0); digc[lane] = dg;
    if (lane < 17) {
      const int i2 = 64 + lane;
      float w[9]; int dg2 = -1;
      #pragma unroll
      for (int e = 0; e < 9; ++e) w[e] = xb[i2 * 9 + e];
      #pragma unroll
      for (int e = 0; e < 9; ++e) { if (w[e] > 0.5f) dg2 = e; ob[i2 * 9 + e] = w[e]; }
      eB = (dg2 < 0); digc[i2] = dg2;
    }
  }
  const int distA = dist_row(lane);
  const int distB = (lane < 17) ? dist_row(64 + lane) : 0;
  const int srow = lane / 9;        // slot row (lane<27)
  const int sdig = lane - 9 * srow; // slot digit
  cbar();

  // initial group counts (27 lanes)
  if (lane < 27) {
    float c9[9];
    #pragma unroll
    for (int e = 0; e < 9; ++e) c9[e] = 0.f;
    #pragma unroll
    for (int k = 0; k < 9; ++k) {
      int cell;
      if (srow == 0)      cell = sdig * 9 + k;
      else if (srow == 1) cell = k * 9 + sdig;
      else cell = (sdig / 3) * 27 + (sdig % 3) * 3 + (k / 3) * 9 + (k % 3);
      const int dg = digc[cell];
      #pragma unroll
      for (int e = 0; e < 9; ++e) c9[e] += (dg == e) ? 1.f : 0.f;
    }
    #pragma unroll
    for (int e = 0; e < 9; ++e) cnt[srow][sdig][e] = c9[e];
  }
  cbar();

  // ---- update 3 rows: fresh fp64 MLP + scatter-reduce + LDS softmax ----
  auto update_rows = [&](int u0, int u1, int u2) {
    double hAv[3], hBv[3];
    #pragma unroll
    for (int rr = 0; rr < 3; ++rr) {
      const int u = (rr == 0) ? u0 : (rr == 1) ? u1 : u2;
      int g, gia, gib, gic;
      if (u < 9)       { g = 0; gia = gib = gic = u; }
      else if (u < 12) { g = 1; gia = 3 * (u - 9); gib = gia + 1; gic = gia + 2; }
      else             { g = 2; gia = gib = gic = u - 12; }
      const float* f0 = &cnt[g][gia][0];
      const float* f1 = &cnt[g][gib][0];
      const float* f2 = &cnt[g][gic][0];
      // 6 independent 9-deep fp64 chains (latency), merged after
      double a00 = 0.0, a01 = 0.0, a02 = 0.0;
      double a10 = 0.0, a11 = 0.0, a12 = 0.0;
      #pragma unroll
      for (int c = 0; c < 9; ++c) {
        const double v0 = (double)f0[c], v1 = (double)f1[c], v2 = (double)f2[c];
        a00 = fma(v0, (double)w1a[c], a00);
        a01 = fma(v1, (double)w1a[9 + c], a01);
        a02 = fma(v2, (double)w1a[18 + c], a02);
        a10 = fma(v0, (double)w1b[c], a10);
        a11 = fma(v1, (double)w1b[9 + c], a11);
        a12 = fma(v2, (double)w1b[18 + c], a12);
      }
      hAv[rr] = fmax((a00 + a01) + a02, 0.0);
      hBv[rr] = fmax((a10 + a11) + a12, 0.0);
    }

    // scatter partials: pp[row*9+digit][lane]
    #pragma unroll
    for (int dd = 0; dd < 9; ++dd) {
      pp[dd][lane]      = fma(hAv[0], w2Ad[dd], hBv[0] * w2Bd[dd]);
      pp[9 + dd][lane]  = fma(hAv[1], w2Ad[dd], hBv[1] * w2Bd[dd]);
      pp[18 + dd][lane] = fma(hAv[2], w2Ad[dd], hBv[2] * w2Bd[dd]);
    }
    cbar();

    // owner-lane reduce (lane<27): 4 accumulator chains
    if (lane < 27) {
      const double2* prow = (const double2*)&pp[lane][0];
      double a0 = 0.0, a1 = 0.0, a2 = 0.0, a3 = 0.0;
      #pragma unroll
      for (int g = 0; g < 32; g += 4) {
        const double2 v0 = prow[g],     v1 = prow[g + 1];
        const double2 v2 = prow[g + 2], v3 = prow[g + 3];
        a0 += v0.x + v0.y; a1 += v1.x + v1.y;
        a2 += v2.x + v2.y; a3 += v3.x + v3.y;
      }
      ylds[lane] = (a0 + a1) + (a2 + a3);
    }
    cbar();

    // softmax pt1: local ymax/argmax, one exp per slot lane
    if (lane < 27) {
      const double* yrow = &ylds[9 * srow];
      double y9[9];
      #pragma unroll
      for (int k = 0; k < 9; ++k) y9[k] = yrow[k];
      double ymax = y9[0]; int yarg = 0;
      #pragma unroll
      for (int k = 1; k < 9; ++k) {
        const bool g = y9[k] > ymax;   // strict > keeps first max (np argmax)
        ymax = g ? y9[k] : ymax;
        yarg = g ? k : yarg;
      }
      if (sdig == 0) {
        const int us = (srow == 0) ? u0 : (srow == 1) ? u1 : u2;
        rargsL[us] = yarg;
      }
      elds[lane] = exp(y9[sdig] - ymax);
    }
    cbar();

    // softmax pt2: ascending sum, sval, score = 1/S (stabilizer = row max)
    if (lane < 27) {
      const double* erow = &elds[9 * srow];
      double S = erow[0];
      #pragma unroll
      for (int k = 1; k < 9; ++k) S += erow[k];
      const double sval = elds[lane] / S;
      const int us = (srow == 0) ? u0 : (srow == 1) ? u1 : u2;
      sful[us][sdig] = (float)sval;
      if (sdig == 0) rscoreL[us] = 1.0 / S;
    }
    cbar();
  };

  // ---- initial 21 rows ----
  #pragma unroll 1
  for (int p = 0; p < 7; ++p) update_rows(3 * p, 3 * p + 1, 3 * p + 2);

  // ---- solver steps ----
  #pragma unroll 1
  for (int step = 0; step < 81; ++step) {
    // Phase A: u64-monotone key argmax, DPP butterfly on (hi,lo) u32 pair.
    const double sAd = eA ? rscoreL[distA] : 0.0;
    const double sBd = (lane < 17 && eB) ? rscoreL[distB] : 0.0;
    const unsigned long long kA = __double_as_longlong(sAd);
    const unsigned long long kB = __double_as_longlong(sBd);
    const unsigned hiA = (unsigned)(kA >> 32), loA = (unsigned)kA;
    const unsigned hiB = (unsigned)(kB >> 32), loB = (unsigned)kB;
    unsigned mh = hiA, ml = loA;
    {
      const bool g = (hiB > mh) | ((hiB == mh) & (loB > ml));
      mh = g ? hiB : mh; ml = g ? loB : ml;
    }
#define ASTEP_DPP(CTRL)                                                        \
    {                                                                          \
      unsigned h2 = (unsigned)__builtin_amdgcn_update_dpp(                     \
          0, (int)mh, CTRL, 0xF, 0xF, true);                                   \
      unsigned l2 = (unsigned)__builtin_amdgcn_update_dpp(                     \
          0, (int)ml, CTRL, 0xF, 0xF, true);                                   \
      const bool g = (h2 > mh) | ((h2 == mh) & (l2 > ml));                     \
      mh = g ? h2 : mh; ml = g ? l2 : ml;                                      \
    }
    ASTEP_DPP(0xB1)   // xor1 (quad_perm)
    ASTEP_DPP(0x4E)   // xor2 (quad_perm)
    ASTEP_DPP(0x124)  // row_ror:4 (quads uniform -> pairwise quad merge)
    ASTEP_DPP(0x128)  // row_ror:8 (completes 16-lane row)
#undef ASTEP_DPP
    {
      unsigned h2 = (unsigned)__builtin_amdgcn_ds_swizzle((int)mh, 0x401F);
      unsigned l2 = (unsigned)__builtin_amdgcn_ds_swizzle((int)ml, 0x401F);
      const bool g = (h2 > mh) | ((h2 == mh) & (l2 > ml));
      mh = g ? h2 : mh; ml = g ? l2 : ml;
    }
    {
      unsigned h2 = (unsigned)__shfl_xor((int)mh, 32);
      unsigned l2 = (unsigned)__shfl_xor((int)ml, 32);
      const bool g = (h2 > mh) | ((h2 == mh) & (l2 > ml));
      mh = g ? h2 : mh; ml = g ? l2 : ml;
    }
    if ((mh | ml) == 0u) break;       // board solved (uniform)

    const unsigned long long m0 = __ballot(eA && (hiA == mh) && (loA == ml));
    const unsigned long long m1 =
        __ballot((lane < 17) && eB && (hiB == mh) && (loB == ml));
    const int mmax = m0 ? __builtin_ctzll(m0) : 64 + __builtin_ctzll(m1);

    const int du = dist_row(mmax);
    const int digit = rargsL[du];     // LDS broadcast
    const int r = mmax / 9, c = mmax - 9 * r;
    const int bx = (mmax / 27) * 3 + c / 3;

    // Phase B: count RMW (feeds fresh Phase C), output write, flag clear
    if (lane < 3) {
      const int gi = (lane == 0) ? r : (lane == 1) ? c : bx;
      cnt[lane][gi][digit] += 1.f;
    } else if (lane >= 8 && lane < 17) {
      ob[mmax * 9 + (lane - 8)] = sful[du][lane - 8];
    }
    if (lane == mmax) eA = false;
    if (lane + 64 == mmax) eB = false;
    cbar();

    update_rows(r, 9 + c / 3, 12 + bx);
  }
}

extern "C" void kernel_launch(void* const* d_in, const int* in_sizes, int n_in,
                              void* d_out, int out_size, void* d_ws, size_t ws_size,
                              hipStream_t stream) {
  const float* x  = (const float*)d_in[0];   // [2048][81][9]
  const float* W1 = (const float*)d_in[1];   // [128][27]
  const float* W2 = (const float*)d_in[2];   // [9][128]
  float* out = (float*)d_out;                // [2048][81][9]
  sudoku_solver<<<dim3(2048), dim3(64), 0, stream>>>(x, W1, W2, out);
}